// Round 10
// baseline (101.686 us; speedup 1.0000x reference)
//
#include <hip/hip_runtime.h>
#include <math.h>

typedef unsigned short ushort_t;
typedef unsigned int uint_t;
typedef __attribute__((ext_vector_type(8))) short bf16x8;
typedef __attribute__((ext_vector_type(16))) float f32x16;

// Problem constants (from reference)
constexpr int Bc   = 8;
constexpr int Nn   = 4500;
constexpr int Ec   = 72000;
constexpr int D    = 128;          // IN_DIM == OUT_DIM == 128
constexpr int T    = Bc * Nn;      // 36000 total nodes
constexpr int TE   = Bc * Ec;      // 576000 total edges
constexpr float EPS = 1e-5f;

constexpr int PAD = 32;            // ints per counter slot (128B line)
constexpr int RST = 128;           // edata slots per node (fixed-stride rows)

// Prep zones: W split | cntp zero
constexpr int NB_W    = 64;                    // 16384 W elems / 256
constexpr int NB_Z    = (T * PAD / 4) / 256;   // 1125 (int4 zero)
constexpr int NB_PREP = NB_W + NB_Z;           // 1189

// Workspace layout (bytes), ~60.3 MB total.
constexpr size_t WS_CNTP  = 0;            // T*PAD i32 = 4,608,000
constexpr size_t WS_EDATA = 4608000;      // T*RST int2 = 36,864,000
constexpr size_t WS_DINV  = 41472000;     // T f32 = 144,000
constexpr size_t WS_Q     = 41616000;     // T f32 = 144,000
constexpr size_t WS_YHI   = 41760000;     // T*D bf16 = 9,216,000
constexpr size_t WS_YLO   = 50976000;     // T*D bf16 = 9,216,000
constexpr size_t WS_WHI   = 60192000;     // 128*128 bf16 = 32,768
constexpr size_t WS_WLO   = 60224768;     // 128*128 bf16 = 32,768

__device__ __forceinline__ ushort_t f32_to_bf16_rne(float f) {
  uint_t u = __float_as_uint(f);
  uint_t r = (u + 0x7fffu + ((u >> 16) & 1u)) >> 16;
  return (ushort_t)r;
}
__device__ __forceinline__ float bf16_to_f32(ushort_t h) {
  return __uint_as_float(((uint_t)h) << 16);
}

// ---------------------------------------------------------------------------
// Prep (zoned): [0,64) W -> bf16 hi/lo; [64,1189) zero cntp (int4).
// ---------------------------------------------------------------------------
__global__ __launch_bounds__(256) void prep_kernel(
    const float* __restrict__ W, ushort_t* __restrict__ Whi,
    ushort_t* __restrict__ Wlo, int4* __restrict__ cntp4) {
  const int bid = blockIdx.x;
  if (bid < NB_W) {
    int i = bid * 256 + threadIdx.x;
    float w = W[i];
    ushort_t hi = f32_to_bf16_rne(w);
    Whi[i] = hi;
    Wlo[i] = f32_to_bf16_rne(w - bf16_to_f32(hi));
  } else {
    int i = (bid - NB_W) * 256 + threadIdx.x;
    cntp4[i] = make_int4(0, 0, 0, 0);
  }
}

// ---------------------------------------------------------------------------
// Edge pass: rk = fetch-add on padded counter; fixed-stride placement
// edata[tgt*RST + rk] = {src_global, bits(ew)}.
// ---------------------------------------------------------------------------
__global__ __launch_bounds__(256) void edge_kernel(
    const int* __restrict__ ei, const float* __restrict__ em,
    int* __restrict__ cntp, int2* __restrict__ edata) {
  int e = blockIdx.x * 256 + threadIdx.x;
  if (e >= TE) return;
  int b  = e / Ec;
  int el = e - b * Ec;
  const int* eb = ei + b * 2 * Ec;
  int t0 = eb[Ec + el];
  if ((unsigned)t0 >= (unsigned)Nn) return;     // defensive
  int tg = t0 + b * Nn;
  int rk = atomicAdd(&cntp[(size_t)tg * PAD], 1);
  if (rk >= RST) return;                        // defensive (P ~ 0)
  int s0 = eb[el];
  float ew = em[e];
  int sg = s0 + b * Nn;
  if ((unsigned)s0 >= (unsigned)Nn) { sg = 0; ew = 0.f; }
  edata[(size_t)tg * RST + rk] = make_int2(sg, __float_as_int(ew));
}

// ---------------------------------------------------------------------------
// deg/dinv: sum ew over the node's edata row; dinv = 1/sqrt(deg+1).
// ---------------------------------------------------------------------------
__global__ __launch_bounds__(256) void deg_dinv_kernel(
    const int2* __restrict__ edata, const int* __restrict__ cntp,
    float* __restrict__ dinv) {
  int i = blockIdx.x * 256 + threadIdx.x;
  if (i >= T) return;
  int cnt = cntp[(size_t)i * PAD];
  cnt = (cnt > RST) ? RST : cnt;
  const int2* row = edata + (size_t)i * RST;
  float s = 0.f;
  for (int j = 0; j < cnt; ++j) s += __int_as_float(row[j].y);
  dinv[i] = 1.0f / sqrtf(s + 1.0f);
}

// ---------------------------------------------------------------------------
// Gather in x-space (GEMM commuted past aggregation):
//   y[t] = x[t]*(1+dt) + dt * sum_s (dinv[s]*ew) x[s]   -> bf16 hi/lo
//   q[t] = 1 + dt + dt * sum_s (dinv[s]*ew)
// XCD-pinned: bid%8 = batch (2.3MB x slice -> per-XCD L2). 32 lanes x float4
// per row; lane-half processes alternating slots; fold via shfl_xor(32).
// ---------------------------------------------------------------------------
__global__ __launch_bounds__(256) void gather_x_kernel(
    const float* __restrict__ x, const int* __restrict__ cntp,
    const int2* __restrict__ edata, const float* __restrict__ dinv,
    ushort_t* __restrict__ yhi, ushort_t* __restrict__ ylo,
    float* __restrict__ q) {
  const int bid  = blockIdx.x;                  // 9000 = 8 * 1125
  const int wid  = threadIdx.x >> 6;
  const int node = (bid & 7) * Nn + (bid >> 3) * 4 + wid;
  const int lane = threadIdx.x & 63;
  const int f4   = lane & 31;
  const int half = lane >> 5;

  const float4* x4 = (const float4*)x;
  int cnt = cntp[(size_t)node * PAD];
  cnt = (cnt > RST) ? RST : cnt;
  const int2* row = edata + (size_t)node * RST;

  float4 xv = x4[(size_t)node * 32 + f4];

  float4 accE = make_float4(0.f, 0.f, 0.f, 0.f);
  float accQ = 0.f;
  int i = half;
  for (; i + 6 < cnt; i += 8) {
    int2 e0 = row[i];
    int2 e1 = row[i + 2];
    int2 e2 = row[i + 4];
    int2 e3 = row[i + 6];
    float c0 = dinv[e0.x] * __int_as_float(e0.y);
    float c1 = dinv[e1.x] * __int_as_float(e1.y);
    float c2 = dinv[e2.x] * __int_as_float(e2.y);
    float c3 = dinv[e3.x] * __int_as_float(e3.y);
    float4 v0 = x4[(size_t)e0.x * 32 + f4];
    float4 v1 = x4[(size_t)e1.x * 32 + f4];
    float4 v2 = x4[(size_t)e2.x * 32 + f4];
    float4 v3 = x4[(size_t)e3.x * 32 + f4];
    accQ += c0 + c1 + c2 + c3;
    accE.x += v0.x * c0 + v1.x * c1 + v2.x * c2 + v3.x * c3;
    accE.y += v0.y * c0 + v1.y * c1 + v2.y * c2 + v3.y * c3;
    accE.z += v0.z * c0 + v1.z * c1 + v2.z * c2 + v3.z * c3;
    accE.w += v0.w * c0 + v1.w * c1 + v2.w * c2 + v3.w * c3;
  }
  for (; i < cnt; i += 2) {
    int2 e0 = row[i];
    float c0 = dinv[e0.x] * __int_as_float(e0.y);
    float4 v0 = x4[(size_t)e0.x * 32 + f4];
    accQ += c0;
    accE.x += v0.x * c0;
    accE.y += v0.y * c0;
    accE.z += v0.z * c0;
    accE.w += v0.w * c0;
  }

  accE.x += __shfl_xor(accE.x, 32);
  accE.y += __shfl_xor(accE.y, 32);
  accE.z += __shfl_xor(accE.z, 32);
  accE.w += __shfl_xor(accE.w, 32);
  accQ   += __shfl_xor(accQ, 32);

  const float dt = dinv[node];
  float4 y;
  y.x = xv.x * (1.f + dt) + dt * accE.x;
  y.y = xv.y * (1.f + dt) + dt * accE.y;
  y.z = xv.z * (1.f + dt) + dt * accE.z;
  y.w = xv.w * (1.f + dt) + dt * accE.w;

  if (half == 0) {
    ushort4 hi, lo;
    hi.x = f32_to_bf16_rne(y.x); lo.x = f32_to_bf16_rne(y.x - bf16_to_f32(hi.x));
    hi.y = f32_to_bf16_rne(y.y); lo.y = f32_to_bf16_rne(y.y - bf16_to_f32(hi.y));
    hi.z = f32_to_bf16_rne(y.z); lo.z = f32_to_bf16_rne(y.z - bf16_to_f32(hi.z));
    hi.w = f32_to_bf16_rne(y.w); lo.w = f32_to_bf16_rne(y.w - bf16_to_f32(hi.w));
    ((ushort4*)yhi)[(size_t)node * 32 + f4] = hi;
    ((ushort4*)ylo)[(size_t)node * 32 + f4] = lo;
    if (f4 == 0) q[node] = 1.f + dt + dt * accQ;
  }
}

// ---------------------------------------------------------------------------
// Fused MFMA GEMM + bias*q + LayerNorm + ReLU + mask -> out.
// Block = 4 waves: 2 row-tiles (64 rows) x 2 col-halves (64 cols each).
// Wave: 32 rows x 64 cols, split-bf16 (3 MFMAs), acc 2x16.
// C/D: col = ch*64 + n*32 + (lane&31), row = (j&3)+8*(j>>2)+4*(lane>>5)
// (verified layout, reused from R5). LN: shfl-reduce over 32 lanes ->
// 1KB LDS exchange across col-halves -> normalize in regs -> store.
// ---------------------------------------------------------------------------
__global__ __launch_bounds__(256) void gemm_ln_kernel(
    const ushort_t* __restrict__ yhi, const ushort_t* __restrict__ ylo,
    const ushort_t* __restrict__ Whi, const ushort_t* __restrict__ Wlo,
    const float* __restrict__ bias, const float* __restrict__ q,
    const float* __restrict__ gamma, const float* __restrict__ beta,
    const float* __restrict__ mask, float* __restrict__ out) {
  __shared__ float2 red[64][2];
  const int wid  = threadIdx.x >> 6;
  const int lane = threadIdx.x & 63;
  const int rt = wid >> 1;                 // row-tile within block
  const int ch = wid & 1;                  // col-half
  const int mt = blockIdx.x * 2 + rt;
  const bool active = (mt < T / 32);       // 1125 row-tiles, 563 blocks
  const int m0 = mt * 32;
  const int r  = lane & 31;
  const int kh = lane >> 5;

  f32x16 acc[2];
#pragma unroll
  for (int n = 0; n < 2; ++n)
#pragma unroll
    for (int j = 0; j < 16; ++j) acc[n][j] = 0.f;

  float e0[16], e1[16];
  const int c0 = ch * 64 + r;
  const int c1 = ch * 64 + 32 + r;

  if (active) {
    const size_t arow = (size_t)(m0 + r) * D + kh * 8;
#pragma unroll
    for (int ks = 0; ks < 8; ++ks) {
      bf16x8 ahi = *(const bf16x8*)(yhi + arow + ks * 16);
      bf16x8 alo = *(const bf16x8*)(ylo + arow + ks * 16);
#pragma unroll
      for (int n = 0; n < 2; ++n) {
        const size_t boff = (size_t)(ch * 64 + n * 32 + r) * D + ks * 16 + kh * 8;
        bf16x8 bhi = *(const bf16x8*)(Whi + boff);
        bf16x8 blo = *(const bf16x8*)(Wlo + boff);
        acc[n] = __builtin_amdgcn_mfma_f32_32x32x16_bf16(ahi, bhi, acc[n], 0, 0, 0);
        acc[n] = __builtin_amdgcn_mfma_f32_32x32x16_bf16(ahi, blo, acc[n], 0, 0, 0);
        acc[n] = __builtin_amdgcn_mfma_f32_32x32x16_bf16(alo, bhi, acc[n], 0, 0, 0);
      }
    }

    const float b0 = bias[c0];
    const float b1 = bias[c1];
#pragma unroll
    for (int j = 0; j < 16; ++j) {
      const int rl = (j & 3) + 8 * (j >> 2) + 4 * kh;
      const float qr = q[m0 + rl];
      e0[j] = acc[0][j] + b0 * qr;
      e1[j] = acc[1][j] + b1 * qr;
      float s  = e0[j] + e1[j];
      float ss = e0[j] * e0[j] + e1[j] * e1[j];
#pragma unroll
      for (int o = 16; o > 0; o >>= 1) {
        s  += __shfl_xor(s, o);
        ss += __shfl_xor(ss, o);
      }
      if (r == 0) red[rt * 32 + rl][ch] = make_float2(s, ss);
    }
  }
  __syncthreads();
  if (active) {
    const float g0  = gamma[c0], g1 = gamma[c1];
    const float be0 = beta[c0],  be1 = beta[c1];
#pragma unroll
    for (int j = 0; j < 16; ++j) {
      const int rl = (j & 3) + 8 * (j >> 2) + 4 * kh;
      const float2 pa = red[rt * 32 + rl][0];
      const float2 pb = red[rt * 32 + rl][1];
      const float mu  = (pa.x + pb.x) * (1.0f / 128.0f);
      const float var = (pa.y + pb.y) * (1.0f / 128.0f) - mu * mu;
      const float rs  = 1.0f / sqrtf(var + EPS);
      const int mrow  = m0 + rl;
      const float m   = mask[mrow];
      out[(size_t)mrow * D + c0] = fmaxf((e0[j] - mu) * rs * g0 + be0, 0.f) * m;
      out[(size_t)mrow * D + c1] = fmaxf((e1[j] - mu) * rs * g1 + be1, 0.f) * m;
    }
  }
}

// ---------------------------------------------------------------------------
extern "C" void kernel_launch(void* const* d_in, const int* in_sizes, int n_in,
                              void* d_out, int out_size, void* d_ws, size_t ws_size,
                              hipStream_t stream) {
  const float* x     = (const float*)d_in[0];
  const int*   ei    = (const int*)d_in[1];
  const float* nmask = (const float*)d_in[2];
  const float* emask = (const float*)d_in[3];
  const float* W     = (const float*)d_in[4];
  const float* bias  = (const float*)d_in[5];
  const float* gamma = (const float*)d_in[6];
  const float* beta  = (const float*)d_in[7];
  float* out = (float*)d_out;

  char*     ws    = (char*)d_ws;
  int*      cntp  = (int*)     (ws + WS_CNTP);
  int2*     edata = (int2*)    (ws + WS_EDATA);
  float*    dinv  = (float*)   (ws + WS_DINV);
  float*    q     = (float*)   (ws + WS_Q);
  ushort_t* yhi   = (ushort_t*)(ws + WS_YHI);
  ushort_t* ylo   = (ushort_t*)(ws + WS_YLO);
  ushort_t* Whi   = (ushort_t*)(ws + WS_WHI);
  ushort_t* Wlo   = (ushort_t*)(ws + WS_WLO);

  prep_kernel<<<NB_PREP, 256, 0, stream>>>(W, Whi, Wlo, (int4*)cntp);
  edge_kernel<<<(TE + 255) / 256, 256, 0, stream>>>(ei, emask, cntp, edata);
  deg_dinv_kernel<<<(T + 255) / 256, 256, 0, stream>>>(edata, cntp, dinv);
  gather_x_kernel<<<T / 4, 256, 0, stream>>>(x, cntp, edata, dinv,
                                             yhi, ylo, q);
  gemm_ln_kernel<<<(T / 32 + 1) / 2, 256, 0, stream>>>(
      yhi, ylo, Whi, Wlo, bias, q, gamma, beta, nmask, out);
}